// Round 4
// baseline (193.119 us; speedup 1.0000x reference)
//
#include <hip/hip_runtime.h>

// Problem constants (fixed by setup_inputs)
#define DIM 512
#define NQ 64
#define BATCH 2048

typedef __bf16  bf16x8  __attribute__((ext_vector_type(8)));
typedef float   floatx4 __attribute__((ext_vector_type(4)));

static __device__ inline unsigned short f2bf(float f) {
    unsigned int u = __float_as_uint(f);
    return (unsigned short)((u + 0x7fffu + ((u >> 16) & 1u)) >> 16);  // RNE
}
static __device__ inline float bf2f(unsigned short h) {
    return __uint_as_float((unsigned int)h << 16);
}
static __device__ inline unsigned int pack2(float a, float b) {
    return (unsigned)f2bf(a) | ((unsigned)f2bf(b) << 16);
}

// Fused pack+expand (round-3 version, unchanged). Grid (512, 5):
//   y = 0..3 : expand q_coefs -> W[k][e][d] (bf16) + npart partials
//   y = 4    : pack points fp32 -> bf16 Pb
__global__ __launch_bounds__(512, 3)
void hsq_expand_kernel(const float* __restrict__ qc,
                       const float* __restrict__ pts,
                       unsigned short* __restrict__ W,
                       unsigned short* __restrict__ Pb,
                       float* __restrict__ npart) {
    const int e = blockIdx.x;             // 0..511

    if (blockIdx.y == 4) {
        const int i4 = e * 512 + threadIdx.x;
        const float4 v = *(const float4*)(pts + (size_t)i4 * 4);
        uint2 wv;
        wv.x = pack2(v.x, v.y); wv.y = pack2(v.z, v.w);
        *(uint2*)(Pb + (size_t)i4 * 4) = wv;
        return;
    }

    const int dblk = blockIdx.y;          // 0..3
    const int pb   = dblk * 512 + e;      // 0..2047
    const int wid  = threadIdx.x >> 6;    // 0..7
    const int k    = threadIdx.x & 63;    // lane = quadric index
    const int d0   = dblk * 128 + wid * 16;

    __shared__ unsigned short tv[64 * 136];
    __shared__ float part[8][64];

    float v[16];
#pragma unroll
    for (int s = 0; s < 16; ++s) {
        const int d = d0 + s;
        const int i = d < e ? d : e;
        const int j = d < e ? e : d;
        const int idx = i * DIM - ((i * (i - 1)) >> 1) + (j - i);
        v[s] = qc[(size_t)idx * NQ + k];
    }

    float nacc = 0.0f;
#pragma unroll
    for (int s = 0; s < 16; ++s)
        if (d0 + s >= e) nacc += v[s] * v[s];

#pragma unroll
    for (int t = 0; t < 2; ++t) {
        float sc[8];
#pragma unroll
        for (int q = 0; q < 8; ++q) {
            const int d = d0 + t * 8 + q;
            sc[q] = v[t * 8 + q] * ((d == e) ? 2.0f : 1.41421356237309515f);
        }
        uint4 w;
        w.x = pack2(sc[0], sc[1]); w.y = pack2(sc[2], sc[3]);
        w.z = pack2(sc[4], sc[5]); w.w = pack2(sc[6], sc[7]);
        *(uint4*)&tv[k * 136 + wid * 16 + t * 8] = w;
    }
    part[wid][k] = nacc;
    __syncthreads();

#pragma unroll
    for (int r = 0; r < 2; ++r) {
        const int kk = r * 32 + (threadIdx.x >> 4);
        const int u  = threadIdx.x & 15;
        const uint4 w = *(const uint4*)&tv[kk * 136 + u * 8];
        *(uint4*)(W + ((size_t)(kk * DIM + e)) * DIM + dblk * 128 + u * 8) = w;
    }
    if (threadIdx.x < 64) {
        npart[(size_t)k * 2048 + pb] =
            part[0][k] + part[1][k] + part[2][k] + part[3][k] +
            part[4][k] + part[5][k] + part[6][k] + part[7][k];
    }
}

// ---------------------------------------------------------------------------
// GEMM v4: BM=256, BN=128, BK=32, 8 waves (4M x 2N), per-wave 64x64 (acc 4x4
// = 64 VGPR). TRIPLE-buffered stages (3 x 24 KB) + 4 KB red = 76 KB LDS ->
// 2 blocks/CU (the m97 cross-block-overlap mechanism; 1-blk/CU 8-phase
// measured 105 us / MfmaUtil 27% -- barrier lockstep with nothing to fill
// bubbles at K=512). __launch_bounds__(512,4) caps VGPR at 128 (est ~120).
// One barrier + one counted vmcnt(3) per K-tile (16 total, was 64); triple
// buffer gives 2-iteration stage lead with NO mid-loop vmcnt(0) drain:
//   prologue: stage(0),(1); vmcnt(3); barrier
//   iter t:   stage(t+2) into buf (t+2)%3 (freed at end of t-1);
//             ds_read frags from buf t%3; 16 MFMA;
//             vmcnt(3) [t+1 landed, t+2 in flight]; barrier
//   t=14: no stage, vmcnt(0); t=15: no stage, no wait.
// LDS layout per buf (12288 ushorts): A [256r][32k] at +0 (8192), B [128r][32k]
// at +8192 (4096). Pair-packed swizzle: two 64B rows per 128B line, byte-in-
// line = (((row&1)<<6) | kbyte) ^ ((line&7)<<4) -- involution applied on the
// pre-swizzled global_load_lds SOURCE (dest stays linear, rule m104/m173) and
// on the frag-read address; replicates round-1's ~zero-conflict geometry.
// ---------------------------------------------------------------------------
__global__ __launch_bounds__(512, 4)
void hsq_gemm_kernel(const unsigned short* __restrict__ Pb,
                     const unsigned short* __restrict__ W,
                     const float* __restrict__ l_coefs,
                     float2* __restrict__ part) {
    extern __shared__ unsigned short smem[];

    // bijective XCD swizzle (2048 % 8 == 0): 256 consecutive wg per XCD = 8 k's
    const int bid = blockIdx.x;
    const int wg  = (bid & 7) * 256 + (bid >> 3);
    const int k   = wg >> 5;              // 0..63
    const int rem = wg & 31;
    const int et  = rem >> 3;             // 0..3  (e-tile of 128)
    const int mt  = rem & 7;              // 0..7  (batch tile of 256)
    const int m0  = mt * 256;

    const int tid  = threadIdx.x;
    const int lane = tid & 63;
    const int w    = tid >> 6;            // 0..7
    const int wm   = w >> 1;              // 0..3 (M group of 64)
    const int wn   = w & 1;               // 0..1 (N group of 64)
    const int c    = lane & 15;
    const int quad = lane >> 4;

    // ---- staging source precompute (linear LDS dest; source pre-swizzled) --
    // A slot cc*512+tid -> line p=slot>>3, logical byte-in-line =
    // ((slot&7)^(p&7))<<4 -> row = 2p + bit6, col = low 6 bits.
    const unsigned short* aptr0;
    const unsigned short* aptr1;
    const unsigned short* bptr;
    {
        int slot = tid;
        int p = slot >> 3;
        int x = ((slot & 7) ^ (p & 7)) << 4;
        aptr0 = Pb + (size_t)(m0 + (p << 1) + (x >> 6)) * DIM + ((x & 63) >> 1);
        slot = 512 + tid;
        p = slot >> 3;
        x = ((slot & 7) ^ (p & 7)) << 4;
        aptr1 = Pb + (size_t)(m0 + (p << 1) + (x >> 6)) * DIM + ((x & 63) >> 1);
        slot = tid;
        p = slot >> 3;                    // 0..63
        x = ((slot & 7) ^ (p & 7)) << 4;
        bptr = W + (size_t)k * DIM * DIM
                 + (size_t)(et * 128 + (p << 1) + (x >> 6)) * DIM + ((x & 63) >> 1);
    }

    // ---- frag read offsets (elements), fixed per thread ----
    int aoff[4], boff[4];
#pragma unroll
    for (int mi = 0; mi < 4; ++mi) {
        const int row  = wm * 64 + mi * 16 + c;
        const int line = row >> 1;
        const int inb  = (((row & 1) << 6) | (quad << 4)) ^ ((line & 7) << 4);
        aoff[mi] = line * 64 + (inb >> 1);
    }
#pragma unroll
    for (int ni = 0; ni < 4; ++ni) {
        const int row  = wn * 64 + ni * 16 + c;
        const int line = row >> 1;
        const int inb  = (((row & 1) << 6) | (quad << 4)) ^ ((line & 7) << 4);
        boff[ni] = line * 64 + (inb >> 1);
    }

#define STAGE3(SB, T) do {                                                     \
    __builtin_amdgcn_global_load_lds(                                          \
        (const __attribute__((address_space(1))) unsigned int*)(aptr0 + (T) * 32), \
        (__attribute__((address_space(3))) unsigned int*)(smem + (SB) * 12288 + tid * 8), \
        16, 0, 0);                                                             \
    __builtin_amdgcn_global_load_lds(                                          \
        (const __attribute__((address_space(1))) unsigned int*)(aptr1 + (T) * 32), \
        (__attribute__((address_space(3))) unsigned int*)(smem + (SB) * 12288 + 4096 + tid * 8), \
        16, 0, 0);                                                             \
    __builtin_amdgcn_global_load_lds(                                          \
        (const __attribute__((address_space(1))) unsigned int*)(bptr + (T) * 32), \
        (__attribute__((address_space(3))) unsigned int*)(smem + (SB) * 12288 + 8192 + tid * 8), \
        16, 0, 0);                                                             \
} while (0)

#define KITER(TB, STAGE_STMT, WAIT_STMT) do {                                  \
    STAGE_STMT;                                                                \
    bf16x8 afr[4], bfr[4];                                                     \
    _Pragma("unroll")                                                          \
    for (int mi = 0; mi < 4; ++mi)                                             \
        afr[mi] = *(const bf16x8*)(smem + (TB) * 12288 + aoff[mi]);            \
    _Pragma("unroll")                                                          \
    for (int ni = 0; ni < 4; ++ni)                                             \
        bfr[ni] = *(const bf16x8*)(smem + (TB) * 12288 + 8192 + boff[ni]);     \
    __builtin_amdgcn_s_setprio(1);                                             \
    _Pragma("unroll")                                                          \
    for (int mi = 0; mi < 4; ++mi)                                             \
        _Pragma("unroll")                                                      \
        for (int ni = 0; ni < 4; ++ni)                                         \
            acc[mi][ni] = __builtin_amdgcn_mfma_f32_16x16x32_bf16(             \
                afr[mi], bfr[ni], acc[mi][ni], 0, 0, 0);                       \
    __builtin_amdgcn_s_setprio(0);                                             \
    WAIT_STMT;                                                                 \
    asm volatile("" ::: "memory");                                             \
    __builtin_amdgcn_s_barrier();                                              \
    asm volatile("" ::: "memory");                                             \
} while (0)

#define VM3  asm volatile("s_waitcnt vmcnt(3)" ::: "memory")
#define VM0  asm volatile("s_waitcnt vmcnt(0)" ::: "memory")

    floatx4 acc[4][4];
#pragma unroll
    for (int mi = 0; mi < 4; ++mi)
#pragma unroll
        for (int ni = 0; ni < 4; ++ni)
            acc[mi][ni] = (floatx4){0.f, 0.f, 0.f, 0.f};

    // prologue: stage tiles 0,1; wait tile0 (leave tile1's 3 in flight)
    STAGE3(0, 0);
    STAGE3(1, 1);
    VM3;
    __builtin_amdgcn_s_barrier();
    asm volatile("" ::: "memory");

#pragma unroll 1
    for (int tt = 0; tt < 12; tt += 3) {
        KITER(0, STAGE3(2, tt + 2), VM3);
        KITER(1, STAGE3(0, tt + 3), VM3);
        KITER(2, STAGE3(1, tt + 4), VM3);
    }
    KITER(0, STAGE3(2, 14), VM3);
    KITER(1, STAGE3(0, 15), VM3);
    KITER(2, ((void)0), VM0);
    KITER(0, ((void)0), ((void)0));

#undef KITER
#undef STAGE3
#undef VM3
#undef VM0

    __syncthreads();

    // ---- Epilogue: pv = sum_e p*(0.5g+l), pg = sum_e (g+l)^2 over this et ---
    float lcv[4];
#pragma unroll
    for (int ni = 0; ni < 4; ++ni)
        lcv[ni] = l_coefs[(et * 128 + wn * 64 + ni * 16 + c) * NQ + k];

    const unsigned short* Pe = Pb + (size_t)(m0 + wm * 64) * DIM + et * 128 + wn * 64 + c;
    float* red = (float*)&smem[36864];    // 2 x 256 x {pv,pg} = 4 KB

#pragma unroll
    for (int mi = 0; mi < 4; ++mi)
#pragma unroll
        for (int r = 0; r < 4; ++r) {
            const unsigned short* Prow = Pe + (size_t)(mi * 16 + quad * 4 + r) * DIM;
            float pv = 0.f, pg = 0.f;
#pragma unroll
            for (int ni = 0; ni < 4; ++ni) {
                const float g = acc[mi][ni][r];
                const float l = lcv[ni];
                pv += bf2f(Prow[ni * 16]) * (0.5f * g + l);
                const float gq = g + l;
                pg += gq * gq;
            }
#pragma unroll
            for (int off = 1; off < 16; off <<= 1) {
                pv += __shfl_xor(pv, off);
                pg += __shfl_xor(pg, off);
            }
            if (c == 0) {
                const int row = wm * 64 + mi * 16 + quad * 4 + r;
                red[(wn * 256 + row) * 2 + 0] = pv;
                red[(wn * 256 + row) * 2 + 1] = pg;
            }
        }
    __syncthreads();

    if (tid < 256) {
        const float pv = red[tid * 2 + 0] + red[(256 + tid) * 2 + 0];
        const float pg = red[tid * 2 + 1] + red[(256 + tid) * 2 + 1];
        part[((size_t)(et * NQ + k)) * BATCH + m0 + tid] = make_float2(pv, pg);
    }
}

// Final: block per k. Reduces npart[k][*] -> norm2 in-block, then combines the
// 4 e-range partials into scores (coalesced reads).
__global__ void hsq_final_kernel(const float2* __restrict__ part,
                                 const float* __restrict__ npart,
                                 const float* __restrict__ free_coefs,
                                 float* __restrict__ out) {
    const int k = blockIdx.x;
    const int t = threadIdx.x;
    __shared__ float ws[4];

    const float4* src = (const float4*)(npart + (size_t)k * 2048);
    const float4 a = src[t * 2], b = src[t * 2 + 1];
    float s = a.x + a.y + a.z + a.w + b.x + b.y + b.z + b.w;
#pragma unroll
    for (int off = 1; off < 64; off <<= 1) s += __shfl_xor(s, off);
    if ((t & 63) == 0) ws[t >> 6] = s;
    __syncthreads();
    const float nrm = sqrtf(ws[0] + ws[1] + ws[2] + ws[3]);
    const float fc  = free_coefs[k];

#pragma unroll
    for (int i = 0; i < 8; ++i) {
        const int bidx = i * 256 + t;
        float pv = 0.f, pg = 0.f;
#pragma unroll
        for (int eb = 0; eb < 4; ++eb) {
            const float2 p = part[((size_t)(eb * NQ + k)) * BATCH + bidx];
            pv += p.x; pg += p.y;
        }
        const float vals = fabsf(pv + fc);
        out[(size_t)bidx * NQ + k] = (sqrtf(0.25f * pg + vals * nrm) - 0.5f * sqrtf(pg)) / nrm;
    }
}

extern "C" void kernel_launch(void* const* d_in, const int* in_sizes, int n_in,
                              void* d_out, int out_size, void* d_ws, size_t ws_size,
                              hipStream_t stream) {
    const float* points     = (const float*)d_in[0];  // (2048, 512)
    const float* q_coefs    = (const float*)d_in[1];  // (131328, 64)
    const float* l_coefs    = (const float*)d_in[2];  // (512, 64)
    const float* free_coefs = (const float*)d_in[3];  // (1, 64)
    float* out = (float*)d_out;                       // (2048, 64)

    char* ws = (char*)d_ws;
    unsigned short* W  = (unsigned short*)ws;                              // 32 MiB
    unsigned short* Pb = (unsigned short*)(ws + 33554432);                 // 2 MiB
    float2*         part  = (float2*)(ws + 35651584);                      // 4 MiB
    float*          npart = (float*)(ws + 39845888);                       // 512 KiB

    // 76 KiB dynamic LDS (one-time opt-in; not a stream op, graph-safe).
    static bool attr_done = false;
    if (!attr_done) {
        (void)hipFuncSetAttribute((const void*)hsq_gemm_kernel,
                                  hipFuncAttributeMaxDynamicSharedMemorySize,
                                  77824);
        attr_done = true;
    }

    hsq_expand_kernel<<<dim3(512, 5), 512, 0, stream>>>(q_coefs, points, W, Pb, npart);
    hsq_gemm_kernel<<<dim3(2048), dim3(512), 77824, stream>>>(Pb, W, l_coefs, part);
    hsq_final_kernel<<<dim3(NQ), 256, 0, stream>>>(part, npart, free_coefs, out);
}

// Round 5
// 187.710 us; speedup vs baseline: 1.0288x; 1.0288x over previous
//
#include <hip/hip_runtime.h>

// Problem constants (fixed by setup_inputs)
#define DIM 512
#define NQ 64
#define BATCH 2048

typedef __bf16  bf16x8  __attribute__((ext_vector_type(8)));
typedef float   floatx4 __attribute__((ext_vector_type(4)));

static __device__ inline unsigned short f2bf(float f) {
    unsigned int u = __float_as_uint(f);
    return (unsigned short)((u + 0x7fffu + ((u >> 16) & 1u)) >> 16);  // RNE
}
static __device__ inline float bf2f(unsigned short h) {
    return __uint_as_float((unsigned int)h << 16);
}
static __device__ inline unsigned int pack2(float a, float b) {
    return (unsigned)f2bf(a) | ((unsigned)f2bf(b) << 16);
}

// Fused pack+expand v5. Grid (512, 5):
//   y = 0..3 : expand q_coefs -> W[k][e][d] + npart partials
//   y = 4    : pack points fp32 -> bf16 Pb
// v5 theory: v3/v4 expand read qc as 16 SCALAR 4B/lane loads (256 B/wave per
// instr) -- the classic under-vectorization sink (~75 us for ~100 MB traffic).
// Now: float4/lane loads (1 KB/wave), 4 loads/thread instead of 16, k<->d
// 4x4 transpose IN REGISTERS (4 shfl_xor/pass), LDS written as b64 pairs
// already in W's d-contiguous bf16-pair order. Phase 2 (coalesced W write)
// is bit-identical to v3's proven version.
__global__ __launch_bounds__(512, 3)
void hsq_expand_kernel(const float* __restrict__ qc,
                       const float* __restrict__ pts,
                       unsigned short* __restrict__ W,
                       unsigned short* __restrict__ Pb,
                       float* __restrict__ npart) {
    const int e = blockIdx.x;             // 0..511

    if (blockIdx.y == 4) {
        const int i4 = e * 512 + threadIdx.x;
        const float4 v = *(const float4*)(pts + (size_t)i4 * 4);
        uint2 wv;
        wv.x = pack2(v.x, v.y); wv.y = pack2(v.z, v.w);
        *(uint2*)(Pb + (size_t)i4 * 4) = wv;
        return;
    }

    const int dblk = blockIdx.y;          // 0..3
    const int pb   = dblk * 512 + e;      // 0..2047
    const int tid  = threadIdx.x;
    const int w    = tid >> 6;            // 0..7
    const int lane = tid & 63;
    const int g    = lane >> 4;           // row-slot 0..3 (pre-transpose)
    const int u    = lane & 15;           // k-quad 0..15
    const int d0   = dblk * 128;

    __shared__ unsigned short tv[64 * 136];   // [k][136] (16B-aligned rows)
    __shared__ float part2[8][64];

    float4 nacc4 = {0.f, 0.f, 0.f, 0.f};

    // Phase 1: 4 passes; per pass each wave loads 4 rows x 64 k as float4/lane,
    // transposes 4x4 across lanes (bits 4,5), writes d-contiguous bf16 pairs.
#pragma unroll
    for (int p = 0; p < 4; ++p) {
        const int rloc = p * 32 + w * 4;  // wave's 4-row base this pass
        const int d = d0 + rloc + g;      // this lane's row (pre-transpose)
        const int i = d < e ? d : e;
        const int j = d < e ? e : d;
        const int idx = i * DIM - ((i * (i - 1)) >> 1) + (j - i);
        float4 f = *(const float4*)(qc + (size_t)idx * NQ + u * 4);

        if (d >= e) {                     // per-lane-uniform predicate
            nacc4.x += f.x * f.x; nacc4.y += f.y * f.y;
            nacc4.z += f.z * f.z; nacc4.w += f.w * f.w;
        }
        const float s = (d == e) ? 2.0f : 1.41421356237309515f;
        float4 v = {f.x * s, f.y * s, f.z * s, f.w * s};

        // 4x4 transpose across quartet lanes {u, u+16, u+32, u+48}.
        // Step 1: outer 2x2 blocks across xor-32 (g bit1 <-> elem bit1)
        {
            float s0 = (g & 2) ? v.x : v.z;
            float s1 = (g & 2) ? v.y : v.w;
            const float r0 = __shfl_xor(s0, 32);
            const float r1 = __shfl_xor(s1, 32);
            if (g & 2) { v.x = r0; v.y = r1; } else { v.z = r0; v.w = r1; }
        }
        // Step 2: inner 2x2 across xor-16 (g bit0 <-> elem bit0), per half
        {
            float s0 = (g & 1) ? v.x : v.y;
            float s1 = (g & 1) ? v.z : v.w;
            const float r0 = __shfl_xor(s0, 16);
            const float r1 = __shfl_xor(s1, 16);
            if (g & 1) { v.x = r0; v.z = r1; } else { v.y = r0; v.w = r1; }
        }
        // now lane holds k = u*4+g for rows rloc..rloc+3 (d-consecutive)
        const int k = u * 4 + g;
        uint2 wv;
        wv.x = pack2(v.x, v.y);
        wv.y = pack2(v.z, v.w);
        *(uint2*)&tv[k * 136 + rloc] = wv;   // 8B aligned (136*2=272=16*17)
    }

    // nacc: sum the 4 row-slots of each quartet (k-quad u), then park per-wave
    nacc4.x += __shfl_xor(nacc4.x, 16); nacc4.y += __shfl_xor(nacc4.y, 16);
    nacc4.z += __shfl_xor(nacc4.z, 16); nacc4.w += __shfl_xor(nacc4.w, 16);
    nacc4.x += __shfl_xor(nacc4.x, 32); nacc4.y += __shfl_xor(nacc4.y, 32);
    nacc4.z += __shfl_xor(nacc4.z, 32); nacc4.w += __shfl_xor(nacc4.w, 32);
    if (g == 0) *(float4*)&part2[w][u * 4] = nacc4;
    __syncthreads();

    // Phase 2: coalesced W write (identical to proven v3 structure)
#pragma unroll
    for (int r = 0; r < 2; ++r) {
        const int kk = r * 32 + (tid >> 4);
        const int uu = tid & 15;
        const uint4 ww = *(const uint4*)&tv[kk * 136 + uu * 8];
        *(uint4*)(W + ((size_t)(kk * DIM + e)) * DIM + dblk * 128 + uu * 8) = ww;
    }
    if (tid < 64) {
        npart[(size_t)tid * 2048 + pb] =
            part2[0][tid] + part2[1][tid] + part2[2][tid] + part2[3][tid] +
            part2[4][tid] + part2[5][tid] + part2[6][tid] + part2[7][tid];
    }
}

// ---------------------------------------------------------------------------
// 256x256 8-phase GEMM -- FROZEN at the round-3 version (measured 105.1 /
// 104.8 us, MfmaUtil ~27, FETCH ~25 MB, twice-reproduced). Three structural
// variants (1-blk 8-phase, 2-blk BK=32 triple-buffer) all pin at 26-27%
// MfmaUtil at K=512; GEMM iteration is paused while the ~85 us non-GEMM
// residual is attacked.
// ---------------------------------------------------------------------------
__global__ __launch_bounds__(512, 2)
void hsq_gemm_kernel(const unsigned short* __restrict__ Pb,
                     const unsigned short* __restrict__ W,
                     const float* __restrict__ l_coefs,
                     float2* __restrict__ part) {
    extern __shared__ unsigned short smem[];

    // bijective XCD swizzle (1024 % 8 == 0): consecutive wg on one XCD share k
    const int bid = blockIdx.x;
    const int wg  = (bid & 7) * 128 + (bid >> 3);
    const int k   = wg >> 4;              // 0..63
    const int rem = wg & 15;
    const int et  = rem >> 3;             // 0..1  (e-tile of 256)
    const int mt  = rem & 7;              // 0..7  (batch tile of 256)
    const int m0  = mt * 256;

    const int tid  = threadIdx.x;
    const int lane = tid & 63;
    const int w    = tid >> 6;            // 0..7
    const int wm   = w >> 2;              // 0..1
    const int wn   = w & 3;               // 0..3
    const int c    = lane & 15;
    const int quad = lane >> 4;

    const unsigned short* Wk = W + ((size_t)k * DIM + (size_t)et * 256) * DIM;

    // staging source (linear LDS dest; source carries the swizzle)
    const int scolb = ((tid & 7) * 16) ^ (((tid >> 3) & 7) << 4);   // bytes
    const unsigned short* pAs = Pb + (size_t)(m0 + (tid >> 3)) * DIM + (scolb >> 1);
    const unsigned short* pBs = Wk + (size_t)(tid >> 3) * DIM + (scolb >> 1);

    // frag read offsets (elements); row&7 == c&7 for every frag row
    const int xorv  = (c & 7) << 4;                              // bytes
    const int koff0 = ((0 * 64 + quad * 16) ^ xorv) >> 1;
    const int koff1 = ((1 * 64 + quad * 16) ^ xorv) >> 1;
    const int awoff = wm * 8192 + c * 64;
    const int bwoff = (wn >> 1) * 8192 + (wn & 1) * 4096 + c * 64;

#define STAGE_HALF(LDSELEM, GSRC) do {                                         \
    _Pragma("unroll")                                                          \
    for (int cc_ = 0; cc_ < 2; ++cc_) {                                        \
        __builtin_amdgcn_global_load_lds(                                      \
            (const __attribute__((address_space(1))) unsigned int*)            \
                ((GSRC) + (size_t)(cc_ * 64) * DIM),                           \
            (__attribute__((address_space(3))) unsigned int*)                  \
                (smem + (LDSELEM) + cc_ * 4096 + tid * 8),                     \
            16, 0, 0);                                                         \
    }                                                                          \
} while (0)

#define LOADB(BBASE) do {                                                      \
    _Pragma("unroll")                                                          \
    for (int ni_ = 0; ni_ < 4; ++ni_) {                                        \
        bfr[ni_][0] = *(const bf16x8*)(smem + (BBASE) + bwoff + ni_ * 1024 + koff0); \
        bfr[ni_][1] = *(const bf16x8*)(smem + (BBASE) + bwoff + ni_ * 1024 + koff1); \
    }                                                                          \
} while (0)

#define PHASE(ABASE, MI0, PRE_B, STAGE_AND_WAIT) do {                          \
    bf16x8 a00 = *(const bf16x8*)(smem + (ABASE) + awoff + (MI0) * 1024 + koff0);     \
    bf16x8 a01 = *(const bf16x8*)(smem + (ABASE) + awoff + (MI0) * 1024 + koff1);     \
    bf16x8 a10 = *(const bf16x8*)(smem + (ABASE) + awoff + ((MI0) + 1) * 1024 + koff0); \
    bf16x8 a11 = *(const bf16x8*)(smem + (ABASE) + awoff + ((MI0) + 1) * 1024 + koff1); \
    PRE_B;                                                                     \
    STAGE_AND_WAIT;                                                            \
    asm volatile("" ::: "memory");                                             \
    __builtin_amdgcn_s_barrier();                                              \
    asm volatile("" ::: "memory");                                             \
    __builtin_amdgcn_s_setprio(1);                                             \
    _Pragma("unroll")                                                          \
    for (int ni_ = 0; ni_ < 4; ++ni_) {                                        \
        acc[(MI0)][ni_]     = __builtin_amdgcn_mfma_f32_16x16x32_bf16(a00, bfr[ni_][0], acc[(MI0)][ni_], 0, 0, 0);     \
        acc[(MI0)][ni_]     = __builtin_amdgcn_mfma_f32_16x16x32_bf16(a01, bfr[ni_][1], acc[(MI0)][ni_], 0, 0, 0);     \
        acc[(MI0) + 1][ni_] = __builtin_amdgcn_mfma_f32_16x16x32_bf16(a10, bfr[ni_][0], acc[(MI0) + 1][ni_], 0, 0, 0); \
        acc[(MI0) + 1][ni_] = __builtin_amdgcn_mfma_f32_16x16x32_bf16(a11, bfr[ni_][1], acc[(MI0) + 1][ni_], 0, 0, 0); \
    }                                                                          \
    __builtin_amdgcn_s_setprio(0);                                             \
    asm volatile("" ::: "memory");                                             \
    __builtin_amdgcn_s_barrier();                                              \
    asm volatile("" ::: "memory");                                             \
} while (0)

    floatx4 acc[8][4];
#pragma unroll
    for (int mi = 0; mi < 8; ++mi)
#pragma unroll
        for (int ni = 0; ni < 4; ++ni)
            acc[mi][ni] = (floatx4){0.f, 0.f, 0.f, 0.f};

    bf16x8 bfr[4][2];

    // prologue: buf0 full (kt0) + buf1.B (kt1); wait buf0, leave buf1.B in flight
    STAGE_HALF(0,             pAs);
    STAGE_HALF(8192,          pAs + 128 * DIM);
    STAGE_HALF(16384,         pBs);
    STAGE_HALF(16384 + 8192,  pBs + 128 * DIM);
    STAGE_HALF(49152,         pBs + 64);
    STAGE_HALF(49152 + 8192,  pBs + 128 * DIM + 64);
    asm volatile("s_waitcnt vmcnt(4)" ::: "memory");
    __builtin_amdgcn_s_barrier();
    asm volatile("" ::: "memory");

    for (int it = 0; it < 4; ++it) {
        const unsigned short* pA1 = pAs + (size_t)(2 * it + 1) * 64;
        const unsigned short* pB2 = pBs + (size_t)(2 * it + 2) * 64;
        const unsigned short* pA2 = pAs + (size_t)(2 * it + 2) * 64;
        const unsigned short* pB3 = pBs + (size_t)(2 * it + 3) * 64;

        // ---- K-tile 2*it from buf0 ----
        PHASE(0, 0, LOADB(16384), { STAGE_HALF(32768, pA1); });
        PHASE(0, 2, ((void)0),    { STAGE_HALF(32768 + 8192, pA1 + 128 * DIM); });
        PHASE(0, 4, ((void)0),    { if (it < 3) STAGE_HALF(16384, pB2); });
        PHASE(0, 6, ((void)0), {
            if (it < 3) {
                STAGE_HALF(16384 + 8192, pB2 + 128 * DIM);
                asm volatile("s_waitcnt vmcnt(4)" ::: "memory");
            } else {
                asm volatile("s_waitcnt vmcnt(0)" ::: "memory");
            }
        });
        // ---- K-tile 2*it+1 from buf1 ----
        PHASE(32768, 0, LOADB(49152), { if (it < 3) STAGE_HALF(0, pA2); });
        PHASE(32768, 2, ((void)0),    { if (it < 3) STAGE_HALF(8192, pA2 + 128 * DIM); });
        PHASE(32768, 4, ((void)0),    { if (it < 3) STAGE_HALF(49152, pB3); });
        PHASE(32768, 6, ((void)0), {
            if (it < 3) {
                STAGE_HALF(49152 + 8192, pB3 + 128 * DIM);
                asm volatile("s_waitcnt vmcnt(4)" ::: "memory");
            }
        });
    }
#undef PHASE
#undef LOADB
#undef STAGE_HALF

    __syncthreads();

    // ---- Epilogue: pv = sum_e p*(0.5g+l), pg = sum_e (g+l)^2 over this et ----
    float lcv[4];
#pragma unroll
    for (int ni = 0; ni < 4; ++ni)
        lcv[ni] = l_coefs[(et * 256 + wn * 64 + ni * 16 + c) * NQ + k];

    const unsigned short* Pe = Pb + (size_t)(m0 + wm * 128) * DIM + et * 256 + wn * 64 + c;
    float* red = (float*)smem;   // reuse LDS: 8 waves x 128 rows x {pv,pg} = 8 KB

#pragma unroll
    for (int mi = 0; mi < 8; ++mi)
#pragma unroll
        for (int r = 0; r < 4; ++r) {
            const unsigned short* Prow = Pe + (size_t)(mi * 16 + quad * 4 + r) * DIM;
            float pv = 0.f, pg = 0.f;
#pragma unroll
            for (int ni = 0; ni < 4; ++ni) {
                const float g = acc[mi][ni][r];
                const float l = lcv[ni];
                pv += bf2f(Prow[ni * 16]) * (0.5f * g + l);
                const float gq = g + l;
                pg += gq * gq;
            }
#pragma unroll
            for (int off = 1; off < 16; off <<= 1) {
                pv += __shfl_xor(pv, off);
                pg += __shfl_xor(pg, off);
            }
            if (c == 0) {
                const int row16 = mi * 16 + quad * 4 + r;
                red[(w * 128 + row16) * 2 + 0] = pv;
                red[(w * 128 + row16) * 2 + 1] = pg;
            }
        }
    __syncthreads();

    if (tid < 256) {
        const int row16 = tid & 127;
        const int wmf   = tid >> 7;
        float pv = 0.f, pg = 0.f;
#pragma unroll
        for (int wnf = 0; wnf < 4; ++wnf) {
            const int wi = wmf * 4 + wnf;
            pv += red[(wi * 128 + row16) * 2 + 0];
            pg += red[(wi * 128 + row16) * 2 + 1];
        }
        part[((size_t)(et * NQ + k)) * BATCH + m0 + wmf * 128 + row16] =
            make_float2(pv, pg);
    }
}

// Final: block per k. Reduces npart[k][*] -> norm2 in-block, then combines the
// 2 e-range partials into scores (coalesced reads).
__global__ void hsq_final_kernel(const float2* __restrict__ part,
                                 const float* __restrict__ npart,
                                 const float* __restrict__ free_coefs,
                                 float* __restrict__ out) {
    const int k = blockIdx.x;
    const int t = threadIdx.x;
    __shared__ float ws[4];

    const float4* src = (const float4*)(npart + (size_t)k * 2048);
    const float4 a = src[t * 2], b = src[t * 2 + 1];
    float s = a.x + a.y + a.z + a.w + b.x + b.y + b.z + b.w;
#pragma unroll
    for (int off = 1; off < 64; off <<= 1) s += __shfl_xor(s, off);
    if ((t & 63) == 0) ws[t >> 6] = s;
    __syncthreads();
    const float nrm = sqrtf(ws[0] + ws[1] + ws[2] + ws[3]);
    const float fc  = free_coefs[k];

#pragma unroll
    for (int i = 0; i < 8; ++i) {
        const int bidx = i * 256 + t;
        float pv = 0.f, pg = 0.f;
#pragma unroll
        for (int eb = 0; eb < 2; ++eb) {
            const float2 p = part[((size_t)(eb * NQ + k)) * BATCH + bidx];
            pv += p.x; pg += p.y;
        }
        const float vals = fabsf(pv + fc);
        out[(size_t)bidx * NQ + k] = (sqrtf(0.25f * pg + vals * nrm) - 0.5f * sqrtf(pg)) / nrm;
    }
}

extern "C" void kernel_launch(void* const* d_in, const int* in_sizes, int n_in,
                              void* d_out, int out_size, void* d_ws, size_t ws_size,
                              hipStream_t stream) {
    const float* points     = (const float*)d_in[0];  // (2048, 512)
    const float* q_coefs    = (const float*)d_in[1];  // (131328, 64)
    const float* l_coefs    = (const float*)d_in[2];  // (512, 64)
    const float* free_coefs = (const float*)d_in[3];  // (1, 64)
    float* out = (float*)d_out;                       // (2048, 64)

    char* ws = (char*)d_ws;
    unsigned short* W  = (unsigned short*)ws;                              // 32 MiB
    unsigned short* Pb = (unsigned short*)(ws + 33554432);                 // 2 MiB
    float2*         part  = (float2*)(ws + 35651584);                      // 2 MiB
    float*          npart = (float*)(ws + 37748736);                       // 512 KiB

    // 128 KiB dynamic LDS needs the opt-in (one-time; not a stream op, safe
    // under graph capture).
    static bool attr_done = false;
    if (!attr_done) {
        (void)hipFuncSetAttribute((const void*)hsq_gemm_kernel,
                                  hipFuncAttributeMaxDynamicSharedMemorySize,
                                  131072);
        attr_done = true;
    }

    hsq_expand_kernel<<<dim3(512, 5), 512, 0, stream>>>(q_coefs, points, W, Pb, npart);
    hsq_gemm_kernel<<<dim3(1024), dim3(512), 131072, stream>>>(Pb, W, l_coefs, part);
    hsq_final_kernel<<<dim3(NQ), 256, 0, stream>>>(part, npart, free_coefs, out);
}